// Round 6
// baseline (14.446 us; speedup 1.0000x reference)
//
#include <hip/hip_runtime.h>
#include <hip/hip_bf16.h>

// Problem constants (fixed by setup_inputs)
#define BB  64      // batches
#define NMM 32      // motifs per batch
#define HH  256     // hidden
#define LFD 16      // ligand feature dim
#define NLA 128     // ligand atoms per batch (NMM*4)

// Softmax over motifs (axis=1) is shift-invariant: protein_rep/residue_rep/
// ligand_rep/b_mlp/b_lig terms are constant per batch row and cancel exactly.
// logit[b,m] (up to a per-batch constant) =
//     emb_table[wid[b,m]] . w4  +  motif_feat_sum[b,m] . (W_lig @ w5)
//
// 256 threads/block (R3's proven shape), ONE barrier (R5's win), role-split
// side jobs, dependent wid->emb chain issued first.

__device__ __forceinline__ float dot4(float4 a, float4 b) {
  return a.x * b.x + a.y * b.y + a.z * b.z + a.w * b.w;
}

__global__ __launch_bounds__(256) void score_kernel(
    const float* __restrict__ lig_feat,    // [B*128][16]
    const int*   __restrict__ wids,        // [B*32]
    const float* __restrict__ W_lig,       // [16][256]
    const float* __restrict__ emb_table,   // [501][256]
    const float* __restrict__ W_mlp,       // [1280][1]
    float* __restrict__ out)               // [64*32] vals, then [64*32] idx
{
  const int b = blockIdx.x;
  const int t = threadIdx.x;

  __shared__ float slog[NMM];          // e4 per motif
  __shared__ float smfs[NMM][LFD];     // motif feature sums
  __shared__ float swl5[LFD];          // W_lig @ w5

  // ---- head of the dependent chain: wid for this thread's motif ----
  const int m = t >> 3;                // 8 lanes per motif
  const int c = t & 7;
  const int wid = wids[b * NMM + m];

  // ---- side-role loads issue while the wid gather is in flight ----
  float4 q0, q1, q2, q3;               // t<128: ligand atom row
  if (t < 128) {
    const float4* p = (const float4*)(lig_feat + (size_t)(b * NLA + t) * LFD);
    q0 = p[0]; q1 = p[1]; q2 = p[2]; q3 = p[3];
  }
  const int u = t & 127;               // t>=128: wl5 partial
  const int f = u >> 3;
  const int k = u & 7;
  float4 wl0, wl1, wl2, wl3, wl4, wl5v, wl6, wl7;
  float4 w50, w51, w52, w53, w54, w55, w56, w57;
  if (t >= 128) {
    const float4* wlr = (const float4*)(W_lig + f * HH) + k * 8;
    const float4* w5r = (const float4*)(W_mlp + 4 * HH) + k * 8;
    wl0 = wlr[0]; wl1 = wlr[1]; wl2 = wlr[2]; wl3 = wlr[3];
    wl4 = wlr[4]; wl5v = wlr[5]; wl6 = wlr[6]; wl7 = wlr[7];
    w50 = w5r[0]; w51 = w5r[1]; w52 = w5r[2]; w53 = w5r[3];
    w54 = w5r[4]; w55 = w5r[5]; w56 = w5r[6]; w57 = w5r[7];
  }

  // ---- e4[m] = emb_table[wid] . w4 : 8 lanes per motif, 32 ch each ----
  {
    const float4* er  = (const float4*)(emb_table + (size_t)wid * HH) + c * 8;
    const float4* w4p = (const float4*)(W_mlp + 3 * HH) + c * 8;
    float s = dot4(er[0], w4p[0]) + dot4(er[1], w4p[1])
            + dot4(er[2], w4p[2]) + dot4(er[3], w4p[3])
            + dot4(er[4], w4p[4]) + dot4(er[5], w4p[5])
            + dot4(er[6], w4p[6]) + dot4(er[7], w4p[7]);
    s += __shfl_xor(s, 1); s += __shfl_xor(s, 2); s += __shfl_xor(s, 4);
    if (c == 0) slog[m] = s;
  }

  // ---- finish side roles ----
  if (t < 128) {
    float a[LFD] = {q0.x,q0.y,q0.z,q0.w, q1.x,q1.y,q1.z,q1.w,
                    q2.x,q2.y,q2.z,q2.w, q3.x,q3.y,q3.z,q3.w};
    float ms[LFD];
#pragma unroll
    for (int ff = 0; ff < LFD; ++ff) {
      float v = a[ff];
      v += __shfl_xor(v, 1); v += __shfl_xor(v, 2);   // 4-atom motif sum
      ms[ff] = v;
    }
    if ((t & 3) == 0) {                 // group leader writes (static idx only)
      float4* dst = (float4*)smfs[t >> 2];
      dst[0] = make_float4(ms[0],  ms[1],  ms[2],  ms[3]);
      dst[1] = make_float4(ms[4],  ms[5],  ms[6],  ms[7]);
      dst[2] = make_float4(ms[8],  ms[9],  ms[10], ms[11]);
      dst[3] = make_float4(ms[12], ms[13], ms[14], ms[15]);
    }
  } else {
    float s = dot4(wl0, w50) + dot4(wl1, w51) + dot4(wl2, w52) + dot4(wl3, w53)
            + dot4(wl4, w54) + dot4(wl5v, w55) + dot4(wl6, w56) + dot4(wl7, w57);
    s += __shfl_xor(s, 1); s += __shfl_xor(s, 2); s += __shfl_xor(s, 4);
    if (k == 0) swl5[f] = s;
  }
  __syncthreads();

  // ---- combine + softmax + full stable rank, lanes 0..31 of wave 0 ----
  if (t < NMM) {
    float x = slog[t];
#pragma unroll
    for (int ff = 0; ff < LFD; ++ff) x += smfs[t][ff] * swl5[ff];
    float mx = x;
    mx = fmaxf(mx, __shfl_xor(mx, 1));
    mx = fmaxf(mx, __shfl_xor(mx, 2));
    mx = fmaxf(mx, __shfl_xor(mx, 4));
    mx = fmaxf(mx, __shfl_xor(mx, 8));
    mx = fmaxf(mx, __shfl_xor(mx, 16));
    const float ex = expf(x - mx);
    float sum = ex;
    sum += __shfl_xor(sum, 1); sum += __shfl_xor(sum, 2);
    sum += __shfl_xor(sum, 4); sum += __shfl_xor(sum, 8);
    sum += __shfl_xor(sum, 16);
    const float sc = ex / sum;
    int rank = 0;
#pragma unroll
    for (int j = 0; j < NMM; ++j) {
      const float sj = __shfl(sc, j);
      rank += (sj > sc) || (sj == sc && j < t);
    }
    out[b * NMM + rank] = sc;                        // vals
    out[BB * NMM + b * NMM + rank] = (float)t;       // idx (as float)
  }
}

extern "C" void kernel_launch(void* const* d_in, const int* in_sizes, int n_in,
                              void* d_out, int out_size, void* d_ws, size_t ws_size,
                              hipStream_t stream) {
  const float* lig_feat    = (const float*)d_in[2];
  const int*   ligand_wids = (const int*)d_in[7];
  const float* W_lig       = (const float*)d_in[14];
  const float* emb_table   = (const float*)d_in[16];
  const float* W_mlp       = (const float*)d_in[18];
  float* out = (float*)d_out;

  score_kernel<<<BB, 256, 0, stream>>>(lig_feat, ligand_wids, W_lig,
                                       emb_table, W_mlp, out);
}